// Round 11
// baseline (96.853 us; speedup 1.0000x reference)
//
#include <hip/hip_runtime.h>
#include <hip/hip_bf16.h>

#define EPS 1e-5f
#define NPTS 262144
#define NB 16
#define ACBLK 1024

typedef __attribute__((ext_vector_type(8))) short bf16x8;
typedef __attribute__((ext_vector_type(4))) float f32x4;

// ws float/u32 offsets
#define WS_E    0        // 192 f
#define WS_T    192      // 1024 f
#define WS_W3   1216     // 2048 u32
#define WS_MAXG 3264     // 2048 u32 merged maxima (memset 0 in-graph)
#define WS_SCRM 6480     // 1024*73 f per-block moments(9)+hist(64)

__device__ inline float decodeu(unsigned u){
  unsigned bits = (u & 0x80000000u) ? (u ^ 0x80000000u) : ~u;
  return __uint_as_float(bits);
}
__device__ inline unsigned f2bf(float f){
  unsigned u = __float_as_uint(f);
  return (u + 0x7FFFu + ((u>>16)&1u)) >> 16;
}
__device__ inline unsigned pack2bf(float lo, float hi){
  return (f2bf(hi)<<16) | (f2bf(lo) & 0xFFFFu);
}
__device__ inline unsigned ordu(float v){
  unsigned bits = __float_as_uint(v);
  return bits ^ (unsigned)(((int)bits>>31) | (int)0x80000000);
}

// ---- kAC: fused moments + per-batch directional max of feats@W1'^T ----
// 1024 blocks x 256 thr; block owns 256 points (1/thread, LDS-staged).
// Tail: read-compare-skip global atomicMax merge (no SMAX round trip).
__global__ __launch_bounds__(256) void kAC(const float* __restrict__ feats,
                                           const int* __restrict__ bidx,
                                           const float* __restrict__ W1,
                                           const float* __restrict__ g1,
                                           float* __restrict__ wsf) {
  __shared__ unsigned lmax[NB*128];
  __shared__ __align__(16) float4 sfeat[256];
  __shared__ float hist[NB*4];
  __shared__ float red[4*9];
  int tid = threadIdx.x;
  for (int i=tid;i<NB*128;i+=256) lmax[i]=0u;
  if (tid < NB*4) hist[tid]=0.f;
  __syncthreads();
  int p = blockIdx.x*256 + tid;
  float f0=feats[3*p], f1=feats[3*p+1], f2=feats[3*p+2];
  int b = bidx[p];
  sfeat[tid] = make_float4(f0,f1,f2,__int_as_float(b));
  atomicAdd(&hist[b*4+0],f0);
  atomicAdd(&hist[b*4+1],f1);
  atomicAdd(&hist[b*4+2],f2);
  atomicAdd(&hist[b*4+3],1.0f);
  int lane = tid&63, wv = tid>>6;
  { float acc[9]={f0,f1,f2,f0*f0,f0*f1,f0*f2,f1*f1,f1*f2,f2*f2};
    #pragma unroll
    for (int k=0;k<9;k++){
      float v=acc[k];
      v+=__shfl_down(v,32); v+=__shfl_down(v,16); v+=__shfl_down(v,8);
      v+=__shfl_down(v,4);  v+=__shfl_down(v,2);  v+=__shfl_down(v,1);
      if (lane==0) red[wv*9+k]=v;
    }
  }
  __syncthreads();
  // channels: c0 = lane, c1 = lane+64; wave owns disjoint 64-point set
  int c0 = lane, c1 = lane+64;
  float sg0 = (g1[c0]>=0.f)?1.f:-1.f;
  float sg1 = (g1[c1]>=0.f)?1.f:-1.f;
  float w00=W1[3*c0]*sg0, w01=W1[3*c0+1]*sg0, w02=W1[3*c0+2]*sg0;
  float w10=W1[3*c1]*sg1, w11=W1[3*c1+1]*sg1, w12=W1[3*c1+2]*sg1;
  const float4* sp = &sfeat[wv*64];
  float m0[16], m1[16];
  #pragma unroll
  for (int q=0;q<16;q++){ m0[q] = -__builtin_inff(); m1[q] = -__builtin_inff(); }
  #pragma unroll 8
  for (int k=0;k<64;k++){
    float4 f = sp[k];                       // broadcast ds_read_b128
    float v0 = fmaf(f.z,w02,fmaf(f.y,w01,f.x*w00));
    float v1 = fmaf(f.z,w12,fmaf(f.y,w11,f.x*w10));
    int sbb = __builtin_amdgcn_readfirstlane(__float_as_int(f.w));
    switch (sbb){
      case 0:  m0[0]=fmaxf(m0[0],v0);  m1[0]=fmaxf(m1[0],v1);  break;
      case 1:  m0[1]=fmaxf(m0[1],v0);  m1[1]=fmaxf(m1[1],v1);  break;
      case 2:  m0[2]=fmaxf(m0[2],v0);  m1[2]=fmaxf(m1[2],v1);  break;
      case 3:  m0[3]=fmaxf(m0[3],v0);  m1[3]=fmaxf(m1[3],v1);  break;
      case 4:  m0[4]=fmaxf(m0[4],v0);  m1[4]=fmaxf(m1[4],v1);  break;
      case 5:  m0[5]=fmaxf(m0[5],v0);  m1[5]=fmaxf(m1[5],v1);  break;
      case 6:  m0[6]=fmaxf(m0[6],v0);  m1[6]=fmaxf(m1[6],v1);  break;
      case 7:  m0[7]=fmaxf(m0[7],v0);  m1[7]=fmaxf(m1[7],v1);  break;
      case 8:  m0[8]=fmaxf(m0[8],v0);  m1[8]=fmaxf(m1[8],v1);  break;
      case 9:  m0[9]=fmaxf(m0[9],v0);  m1[9]=fmaxf(m1[9],v1);  break;
      case 10: m0[10]=fmaxf(m0[10],v0); m1[10]=fmaxf(m1[10],v1); break;
      case 11: m0[11]=fmaxf(m0[11],v0); m1[11]=fmaxf(m1[11],v1); break;
      case 12: m0[12]=fmaxf(m0[12],v0); m1[12]=fmaxf(m1[12],v1); break;
      case 13: m0[13]=fmaxf(m0[13],v0); m1[13]=fmaxf(m1[13],v1); break;
      case 14: m0[14]=fmaxf(m0[14],v0); m1[14]=fmaxf(m1[14],v1); break;
      default: m0[15]=fmaxf(m0[15],v0); m1[15]=fmaxf(m1[15],v1); break;
    }
  }
  #pragma unroll
  for (int q=0;q<16;q++){
    if (m0[q] > -__builtin_inff()) atomicMax(&lmax[q*128+c0], ordu(m0[q]));
    if (m1[q] > -__builtin_inff()) atomicMax(&lmax[q*128+c1], ordu(m1[q]));
  }
  __syncthreads();
  float* scrM = wsf + WS_SCRM + blockIdx.x*73;
  if (tid<9) scrM[tid]=red[tid]+red[9+tid]+red[18+tid]+red[27+tid];
  if (tid>=64 && tid<128) scrM[9+tid-64]=hist[tid-64];
  // global merge: read-compare-skip; stale reads only cause extra no-op atomics
  { unsigned* mg = (unsigned*)wsf + WS_MAXG;
    for (int i=tid;i<2048;i+=256){
      unsigned v = lmax[i];
      if (v > mg[i]) atomicMax(&mg[i], v);
    } }
}

// ---- kB: all tiny math (single block, 1024 thr, float4 LDS dots) ----
__global__ __launch_bounds__(1024) void kB(float* __restrict__ wsf,
    const float* __restrict__ W1, const float* __restrict__ g1, const float* __restrict__ b1,
    const float* __restrict__ W2, const float* __restrict__ g2, const float* __restrict__ b2,
    const float* __restrict__ W3) {
  __shared__ __align__(16) float4 w2q[64*66];
  __shared__ __align__(16) float4 smbnq[NB*32];
  __shared__ __align__(16) float4 srhsq[4*32];
  __shared__ float s_w1[384];
  __shared__ float s_sc[128], s_sh[128], sE[3*64], sg[64], sT[NB*64];
  __shared__ float smom[80], s_s2[64], s_t2[64];
  __shared__ float pmred[73*8];
  int tid = threadIdx.x;
  float4 rw[4];
  #pragma unroll
  for (int t=0;t<4;t++) rw[t] = ((const float4*)W2)[tid + t*1024];
  float4 rw3 = ((const float4*)W3)[tid];
  if (tid<384) s_w1[tid]=W1[tid];
  // parallel moment reduce: 73 moments x 8 partials x 128 blocks each
  { int m = tid>>3, g = tid&7;
    if (m<73){
      float s=0; const float* sm0=wsf+WS_SCRM;
      for (int k=g*128;k<(g+1)*128;k++) s += sm0[k*73+m];
      pmred[m*8+g]=s;
    } }
  #pragma unroll
  for (int t=0;t<4;t++){
    int q = tid + t*1024;
    w2q[(q&63)*66 + (q>>6)] = rw[t];
  }
  { unsigned* w3u = (unsigned*)wsf + WS_W3;
    w3u[2*tid]   = pack2bf(rw3.x, rw3.y);
    w3u[2*tid+1] = pack2bf(rw3.z, rw3.w);
  }
  __syncthreads();
  if (tid<73){
    float s=0;
    #pragma unroll
    for (int g=0;g<8;g++) s += pmred[tid*8+g];
    smom[tid]=s;
  }
  __syncthreads();
  const float invN = 1.0f/NPTS;
  if (tid < 128){
    int c=tid; float w0=s_w1[3*c],w1=s_w1[3*c+1],w2=s_w1[3*c+2];
    float mean = (w0*smom[0]+w1*smom[1]+w2*smom[2])*invN;
    float ex2 = (w0*w0*smom[3]+w1*w1*smom[6]+w2*w2*smom[8]
               + 2.f*(w0*w1*smom[4]+w0*w2*smom[5]+w1*w2*smom[7]))*invN;
    float var = ex2 - mean*mean;
    float sc = g1[c]*rsqrtf(var+EPS);
    s_sc[c]=sc; s_sh[c]=b1[c]-mean*sc;
  }
  __syncthreads();
  { const unsigned* mg=(const unsigned*)wsf+WS_MAXG;
    float* smbnf = (float*)smbnq;
    #pragma unroll
    for (int i=tid;i<NB*128;i+=1024){
      float M = decodeu(mg[i]);
      int ch=i&127;
      smbnf[i] = fabsf(s_sc[ch])*M + s_sh[ch];
    } }
  if (tid < 512){
    int which = tid>>7, j = tid&127;
    ((float*)srhsq)[tid] = (which<3) ? s_sc[j]*s_w1[3*j+which] : s_sh[j];
  }
  __syncthreads();
  { int c = tid&63, b = tid>>6;
    const float4* rq = &smbnq[b*32];
    float s=0;
    #pragma unroll 8
    for (int jj=0;jj<32;jj++){
      float4 a = w2q[(32+jj)*66 + c];
      float4 r = rq[jj];
      s = fmaf(a.x,r.x,fmaf(a.y,r.y,fmaf(a.z,r.z,fmaf(a.w,r.w,s))));
    }
    sT[b*64+c] = s;
    if (tid < 256){
      int which = tid>>6;
      float s2=0;
      #pragma unroll 8
      for (int jj=0;jj<32;jj++){
        float4 a = w2q[jj*66 + c];
        float4 r = srhsq[which*32+jj];
        s2 = fmaf(a.x,r.x,fmaf(a.y,r.y,fmaf(a.z,r.z,fmaf(a.w,r.w,s2))));
      }
      if (which<3) sE[which*64+c]=s2; else sg[c]=s2;
    }
  }
  __syncthreads();
  if (tid < 64){
    int c=tid;
    float e0=sE[c],e1=sE[64+c],e2=sE[128+c],gc=sg[c];
    float sumY = e0*smom[0]+e1*smom[1]+e2*smom[2];
    float sumYY = e0*e0*smom[3]+e1*e1*smom[6]+e2*e2*smom[8]
               + 2.f*(e0*e1*smom[4]+e0*e2*smom[5]+e1*e2*smom[7]);
    #pragma unroll
    for (int b=0;b<NB;b++){
      float nb = smom[9+b*4+3];
      float hb = gc + sT[b*64+c];
      float eS1b = e0*smom[9+b*4]+e1*smom[9+b*4+1]+e2*smom[9+b*4+2];
      sumY += nb*hb;
      sumYY += 2.f*hb*eS1b + nb*hb*hb;
    }
    float mean2 = sumY*invN;
    float var2 = sumYY*invN - mean2*mean2;
    float s2 = g2[c]*rsqrtf(var2+EPS);
    float t2 = b2[c]-mean2*s2;
    s_s2[c]=s2; s_t2[c]=t2;
    wsf[WS_E + c] = e0*s2; wsf[WS_E+64+c]=e1*s2; wsf[WS_E+128+c]=e2*s2;
  }
  __syncthreads();
  { int c=tid&63;
    if (tid < NB*64) wsf[WS_T + tid] = (sg[c]+sT[tid])*s_s2[c] + s_t2[c];
  }
}

// ---- kF: fused y2 -> bn2/relu -> z@W3.T + b3, LDS-transposed coalesced store ----
__global__ __launch_bounds__(256, 4) void kF(const float* __restrict__ feats,
                                             const int* __restrict__ bidx,
                                             const float* __restrict__ wsf,
                                             const float* __restrict__ b3,
                                             float* __restrict__ out) {
  __shared__ __align__(16) unsigned char SB[36992];
  unsigned* zbuf = (unsigned*)SB;            // 32768 B: 4 waves x 64 rows x 128B
  float* Tl = (float*)(SB + 32768);          // 16*66
  float* fbuf = (float*)SB;                  // epilogue: [4][32][68] f32
  int tid = threadIdx.x;
  for (int i=tid;i<NB*64;i+=256) Tl[(i>>6)*66 + (i&63)] = wsf[WS_T + i];
  int lane = tid & 63, wv = tid >> 6;
  int col = lane & 15, kgrp = lane >> 4;
  const ushort* w3b = (const ushort*)((const unsigned*)wsf + WS_W3);
  bf16x8 bfr[4][2];
  #pragma unroll
  for (int n=0;n<4;n++)
    #pragma unroll
    for (int kk=0;kk<2;kk++)
      bfr[n][kk] = *(const bf16x8*)(w3b + (n*16+col)*64 + kk*32 + kgrp*8);
  float bias[4];
  #pragma unroll
  for (int n=0;n<4;n++) bias[n] = b3[n*16+col];
  __syncthreads();
  const float* Eg = wsf + WS_E;
  int p0 = (blockIdx.x*4 + wv)*64;
  int p = p0 + lane;
  float f0 = feats[3*p], f1 = feats[3*p+1], f2 = feats[3*p+2];
  int b = bidx[p];
  const float* tb = &Tl[b*66];
  unsigned rowbase = (unsigned)(wv*64+lane)*32;
  unsigned sw = (lane&7)<<2;
  #pragma unroll
  for (int j=0;j<8;j++){
    unsigned w[4];
    #pragma unroll
    for (int q=0;q<4;q++){
      int c = j*8 + q*2;
      float2 tp = *(const float2*)(tb + c);
      float y0 = fmaf(Eg[c],  f0, fmaf(Eg[64+c],  f1, fmaf(Eg[128+c],  f2, tp.x)));
      float y1 = fmaf(Eg[c+1],f0, fmaf(Eg[64+c+1],f1, fmaf(Eg[128+c+1],f2, tp.y)));
      w[q] = pack2bf(fmaxf(y0,0.f), fmaxf(y1,0.f));
    }
    uint4 ch; ch.x=w[0]; ch.y=w[1]; ch.z=w[2]; ch.w=w[3];
    *(uint4*)&zbuf[rowbase + (((unsigned)(j*4)) ^ sw)] = ch;
  }
  __syncthreads();
  bf16x8 af[4][2];
  #pragma unroll
  for (int m=0;m<4;m++){
    int row = m*16 + col;
    unsigned rb = (unsigned)(wv*64+row)*32;
    unsigned sw2 = (unsigned)(row&7)<<2;
    #pragma unroll
    for (int kk=0;kk<2;kk++){
      unsigned off = ((unsigned)(kk*16 + kgrp*4)) ^ sw2;
      af[m][kk] = *(const bf16x8*)&zbuf[rb + off];
    }
  }
  __syncthreads();
  #pragma unroll
  for (int half=0; half<2; half++){
    f32x4 acc[2][4];
    #pragma unroll
    for (int mi=0;mi<2;mi++)
      #pragma unroll
      for (int n=0;n<4;n++)
        acc[mi][n] = (f32x4){0.f,0.f,0.f,0.f};
    #pragma unroll
    for (int kk=0;kk<2;kk++)
      #pragma unroll
      for (int mi=0;mi<2;mi++)
        #pragma unroll
        for (int n=0;n<4;n++)
          acc[mi][n] = __builtin_amdgcn_mfma_f32_16x16x32_bf16(af[half*2+mi][kk], bfr[n][kk], acc[mi][n], 0,0,0);
    #pragma unroll
    for (int mi=0;mi<2;mi++){
      #pragma unroll
      for (int n=0;n<4;n++){
        #pragma unroll
        for (int r=0;r<4;r++)
          fbuf[wv*2176 + (mi*16 + kgrp*4 + r)*68 + n*16 + col] = acc[mi][n][r] + bias[n];
      }
    }
    __syncthreads();
    #pragma unroll
    for (int it=0; it<8; it++){
      int idx = it*256 + tid;
      int gr = idx >> 4;
      int c4 = (idx & 15) * 4;
      float4 v = *(const float4*)&fbuf[(gr>>5)*2176 + (gr&31)*68 + c4];
      int orow = blockIdx.x*256 + (gr>>5)*64 + half*32 + (gr&31);
      *(float4*)&out[(size_t)orow*64 + c4] = v;
    }
    __syncthreads();
  }
}

extern "C" void kernel_launch(void* const* d_in, const int* in_sizes, int n_in,
                              void* d_out, int out_size, void* d_ws, size_t ws_size,
                              hipStream_t stream) {
  const float* feats = (const float*)d_in[0];
  const int*   bidx  = (const int*)d_in[1];
  const float* W1 = (const float*)d_in[2];
  const float* g1 = (const float*)d_in[3];
  const float* b1 = (const float*)d_in[4];
  const float* W2 = (const float*)d_in[5];
  const float* g2 = (const float*)d_in[6];
  const float* b2 = (const float*)d_in[7];
  const float* W3 = (const float*)d_in[8];
  const float* b3 = (const float*)d_in[9];
  float* wsf = (float*)d_ws;
  float* out = (float*)d_out;
  (void)hipMemsetAsync((char*)d_ws + (size_t)WS_MAXG*4, 0, 2048*4, stream);
  kAC<<<ACBLK, 256, 0, stream>>>(feats, bidx, W1, g1, wsf);
  kB<<<1, 1024, 0, stream>>>(wsf, W1,g1,b1, W2,g2,b2, W3);
  kF<<<ACBLK, 256, 0, stream>>>(feats, bidx, wsf, b3, out);
}

// Round 12
// 62.554 us; speedup vs baseline: 1.5483x; 1.5483x over previous
//
#include <hip/hip_runtime.h>
#include <hip/hip_bf16.h>

#define EPS 1e-5f
#define NPTS 262144
#define NB 16
#define ACBLK 1024

typedef __attribute__((ext_vector_type(8))) short bf16x8;
typedef __attribute__((ext_vector_type(4))) float f32x4;

// ws float/u32 offsets
#define WS_E    0        // 192 f
#define WS_T    192      // 1024 f
#define WS_W3   1216     // 2048 u32
#define WS_MAXF 3264     // 2048 u32 FINAL merged maxima (written by kMx)
#define WS_PMOM 5312     // 16*73 f partial moments (written by kMx)
#define WS_SCRM 6480     // 1024*73 f per-block moments(9)+hist(64)
#define WS_SMAX 81232    // 1024*2048 u32 per-block maxima

__device__ inline float decodeu(unsigned u){
  unsigned bits = (u & 0x80000000u) ? (u ^ 0x80000000u) : ~u;
  return __uint_as_float(bits);
}
__device__ inline unsigned f2bf(float f){
  unsigned u = __float_as_uint(f);
  return (u + 0x7FFFu + ((u>>16)&1u)) >> 16;
}
__device__ inline unsigned pack2bf(float lo, float hi){
  return (f2bf(hi)<<16) | (f2bf(lo) & 0xFFFFu);
}
__device__ inline unsigned ordu(float v){
  unsigned bits = __float_as_uint(v);
  return bits ^ (unsigned)(((int)bits>>31) | (int)0x80000000);
}

// ---- kAC: fused moments + per-batch directional max of feats@W1'^T ----
// (R10 known-good form; SMAX scratch path only)
__global__ __launch_bounds__(256) void kAC(const float* __restrict__ feats,
                                           const int* __restrict__ bidx,
                                           const float* __restrict__ W1,
                                           const float* __restrict__ g1,
                                           float* __restrict__ wsf) {
  __shared__ unsigned lmax[NB*128];
  __shared__ __align__(16) float4 sfeat[256];
  __shared__ float hist[NB*4];
  __shared__ float red[4*9];
  int tid = threadIdx.x;
  for (int i=tid;i<NB*128;i+=256) lmax[i]=0u;
  if (tid < NB*4) hist[tid]=0.f;
  __syncthreads();
  int p = blockIdx.x*256 + tid;
  float f0=feats[3*p], f1=feats[3*p+1], f2=feats[3*p+2];
  int b = bidx[p];
  sfeat[tid] = make_float4(f0,f1,f2,__int_as_float(b));
  atomicAdd(&hist[b*4+0],f0);
  atomicAdd(&hist[b*4+1],f1);
  atomicAdd(&hist[b*4+2],f2);
  atomicAdd(&hist[b*4+3],1.0f);
  int lane = tid&63, wv = tid>>6;
  { float acc[9]={f0,f1,f2,f0*f0,f0*f1,f0*f2,f1*f1,f1*f2,f2*f2};
    #pragma unroll
    for (int k=0;k<9;k++){
      float v=acc[k];
      v+=__shfl_down(v,32); v+=__shfl_down(v,16); v+=__shfl_down(v,8);
      v+=__shfl_down(v,4);  v+=__shfl_down(v,2);  v+=__shfl_down(v,1);
      if (lane==0) red[wv*9+k]=v;
    }
  }
  __syncthreads();
  // channels: c0 = lane, c1 = lane+64; wave owns disjoint 64-point set
  int c0 = lane, c1 = lane+64;
  float sg0 = (g1[c0]>=0.f)?1.f:-1.f;
  float sg1 = (g1[c1]>=0.f)?1.f:-1.f;
  float w00=W1[3*c0]*sg0, w01=W1[3*c0+1]*sg0, w02=W1[3*c0+2]*sg0;
  float w10=W1[3*c1]*sg1, w11=W1[3*c1+1]*sg1, w12=W1[3*c1+2]*sg1;
  const float4* sp = &sfeat[wv*64];
  float m0[16], m1[16];
  #pragma unroll
  for (int q=0;q<16;q++){ m0[q] = -__builtin_inff(); m1[q] = -__builtin_inff(); }
  #pragma unroll 8
  for (int k=0;k<64;k++){
    float4 f = sp[k];                       // broadcast ds_read_b128
    float v0 = fmaf(f.z,w02,fmaf(f.y,w01,f.x*w00));
    float v1 = fmaf(f.z,w12,fmaf(f.y,w11,f.x*w10));
    int sbb = __builtin_amdgcn_readfirstlane(__float_as_int(f.w));
    switch (sbb){
      case 0:  m0[0]=fmaxf(m0[0],v0);  m1[0]=fmaxf(m1[0],v1);  break;
      case 1:  m0[1]=fmaxf(m0[1],v0);  m1[1]=fmaxf(m1[1],v1);  break;
      case 2:  m0[2]=fmaxf(m0[2],v0);  m1[2]=fmaxf(m1[2],v1);  break;
      case 3:  m0[3]=fmaxf(m0[3],v0);  m1[3]=fmaxf(m1[3],v1);  break;
      case 4:  m0[4]=fmaxf(m0[4],v0);  m1[4]=fmaxf(m1[4],v1);  break;
      case 5:  m0[5]=fmaxf(m0[5],v0);  m1[5]=fmaxf(m1[5],v1);  break;
      case 6:  m0[6]=fmaxf(m0[6],v0);  m1[6]=fmaxf(m1[6],v1);  break;
      case 7:  m0[7]=fmaxf(m0[7],v0);  m1[7]=fmaxf(m1[7],v1);  break;
      case 8:  m0[8]=fmaxf(m0[8],v0);  m1[8]=fmaxf(m1[8],v1);  break;
      case 9:  m0[9]=fmaxf(m0[9],v0);  m1[9]=fmaxf(m1[9],v1);  break;
      case 10: m0[10]=fmaxf(m0[10],v0); m1[10]=fmaxf(m1[10],v1); break;
      case 11: m0[11]=fmaxf(m0[11],v0); m1[11]=fmaxf(m1[11],v1); break;
      case 12: m0[12]=fmaxf(m0[12],v0); m1[12]=fmaxf(m1[12],v1); break;
      case 13: m0[13]=fmaxf(m0[13],v0); m1[13]=fmaxf(m1[13],v1); break;
      case 14: m0[14]=fmaxf(m0[14],v0); m1[14]=fmaxf(m1[14],v1); break;
      default: m0[15]=fmaxf(m0[15],v0); m1[15]=fmaxf(m1[15],v1); break;
    }
  }
  #pragma unroll
  for (int q=0;q<16;q++){
    if (m0[q] > -__builtin_inff()) atomicMax(&lmax[q*128+c0], ordu(m0[q]));
    if (m1[q] > -__builtin_inff()) atomicMax(&lmax[q*128+c1], ordu(m1[q]));
  }
  __syncthreads();
  float* scrM = wsf + WS_SCRM + blockIdx.x*73;
  if (tid<9) scrM[tid]=red[tid]+red[9+tid]+red[18+tid]+red[27+tid];
  if (tid>=64 && tid<128) scrM[9+tid-64]=hist[tid-64];
  unsigned* spo = (unsigned*)wsf + WS_SMAX + (size_t)blockIdx.x*2048;
  for (int i=tid;i<2048;i+=256) spo[i]=lmax[i];
}

// ---- kMx: maxima 1024 -> FINAL; moments 1024 -> 16; W3 pack ----
// 64 blocks x 256 thr. Block owns 32 maxima elements; 8 thread-groups
// tree-read coalesced 128B rows of SMAX.
__global__ __launch_bounds__(256) void kMx(const float* __restrict__ W3,
                                           float* __restrict__ wsf){
  __shared__ unsigned red[8][32];
  __shared__ float mred[2][73];
  int tid = threadIdx.x, blk = blockIdx.x;
  int g = tid >> 5;
  int e = blk*32 + (tid & 31);
  const unsigned* smax = (const unsigned*)wsf + WS_SMAX;
  unsigned m = 0;
  #pragma unroll 4
  for (int k=g*128; k<g*128+128; k++){
    unsigned t = smax[(size_t)k*2048 + e];
    m = t>m ? t : m;
  }
  red[g][tid&31] = m;
  // moments partials: blocks 0..15, threads 0..145 (2 halves x 73 moments)
  if (blk < 16 && tid < 146){
    int h = (tid >= 73) ? 1 : 0, mm = tid - 73*h;
    float s = 0; const float* sm0 = wsf + WS_SCRM;
    int k0 = blk*64 + h*32;
    #pragma unroll 4
    for (int k=k0; k<k0+32; k++) s += sm0[k*73 + mm];
    mred[h][mm] = s;
  }
  // W3 pack: blocks 16..19 (1024 threads total, one float4 each)
  if (blk >= 16 && blk < 20){
    int q = (blk-16)*256 + tid;
    float4 v = ((const float4*)W3)[q];
    unsigned* w3u = (unsigned*)wsf + WS_W3;
    w3u[2*q]   = pack2bf(v.x, v.y);
    w3u[2*q+1] = pack2bf(v.z, v.w);
  }
  __syncthreads();
  if (tid < 32){
    unsigned u = red[0][tid];
    #pragma unroll
    for (int q=1;q<8;q++){ unsigned t=red[q][tid]; u = t>u?t:u; }
    ((unsigned*)wsf)[WS_MAXF + blk*32 + tid] = u;
  }
  if (blk < 16 && tid < 73)
    wsf[WS_PMOM + blk*73 + tid] = mred[0][tid] + mred[1][tid];
}

// ---- kB2: per-output-channel layer-2 math. 64 blocks (1/channel) x 128 thr ----
__global__ __launch_bounds__(128) void kB2(const float* __restrict__ W1,
    const float* __restrict__ g1, const float* __restrict__ b1,
    const float* __restrict__ W2, const float* __restrict__ g2,
    const float* __restrict__ b2, float* __restrict__ wsf){
  __shared__ float smom[80];
  __shared__ float dred[2][20];
  int tid = threadIdx.x, c = blockIdx.x;
  int lane = tid & 63, wv = tid >> 6;
  if (tid < 73){
    float s = 0; const float* pm = wsf + WS_PMOM;
    #pragma unroll
    for (int g=0; g<16; g++) s += pm[g*73 + tid];
    smom[tid] = s;
  }
  int j = tid;   // layer-1 feature index this thread owns (0..127)
  float w2f = W2[c*256 + j];          // front half (conv path)
  float w2b = W2[c*256 + 128 + j];    // back half (segmax path)
  float w10 = W1[3*j], w11 = W1[3*j+1], w12 = W1[3*j+2];
  float g1j = g1[j], b1j = b1[j];
  unsigned um[16];
  { const unsigned* mf = (const unsigned*)wsf + WS_MAXF;
    #pragma unroll
    for (int b=0;b<16;b++) um[b] = mf[b*128 + j];
  }
  __syncthreads();
  const float invN = 1.0f/NPTS;
  float mean = (w10*smom[0]+w11*smom[1]+w12*smom[2])*invN;
  float ex2 = (w10*w10*smom[3]+w11*w11*smom[6]+w12*w12*smom[8]
             + 2.f*(w10*w11*smom[4]+w10*w12*smom[5]+w11*w12*smom[7]))*invN;
  float var = ex2 - mean*mean;
  float sc = g1j*rsqrtf(var+EPS);
  float sh = b1j - mean*sc;
  float asc = fabsf(sc);
  float p[20];
  p[0] = w2f*(sc*w10); p[1] = w2f*(sc*w11); p[2] = w2f*(sc*w12); p[3] = w2f*sh;
  #pragma unroll
  for (int b=0;b<16;b++) p[4+b] = w2b * fmaf(asc, decodeu(um[b]), sh);
  #pragma unroll
  for (int k=0;k<20;k++){
    float v = p[k];
    v+=__shfl_down(v,32); v+=__shfl_down(v,16); v+=__shfl_down(v,8);
    v+=__shfl_down(v,4);  v+=__shfl_down(v,2);  v+=__shfl_down(v,1);
    if (lane==0) dred[wv][k] = v;
  }
  __syncthreads();
  if (tid == 0){
    float fin[20];
    #pragma unroll
    for (int k=0;k<20;k++) fin[k] = dred[0][k] + dred[1][k];
    float e0=fin[0], e1=fin[1], e2=fin[2], gc=fin[3];
    float sumY = e0*smom[0]+e1*smom[1]+e2*smom[2];
    float sumYY = e0*e0*smom[3]+e1*e1*smom[6]+e2*e2*smom[8]
               + 2.f*(e0*e1*smom[4]+e0*e2*smom[5]+e1*e2*smom[7]);
    float hbs[16];
    #pragma unroll
    for (int b=0;b<16;b++){
      float nb = smom[9+b*4+3];
      float hb = gc + fin[4+b];
      hbs[b] = hb;
      float eS1b = e0*smom[9+b*4]+e1*smom[9+b*4+1]+e2*smom[9+b*4+2];
      sumY += nb*hb;
      sumYY += 2.f*hb*eS1b + nb*hb*hb;
    }
    float mean2 = sumY*invN;
    float var2 = sumYY*invN - mean2*mean2;
    float s2 = g2[c]*rsqrtf(var2+EPS);
    float t2 = b2[c] - mean2*s2;
    wsf[WS_E + c]      = e0*s2;
    wsf[WS_E + 64 + c] = e1*s2;
    wsf[WS_E + 128 + c]= e2*s2;
    #pragma unroll
    for (int b=0;b<16;b++) wsf[WS_T + b*64 + c] = hbs[b]*s2 + t2;
  }
}

// ---- kF: fused y2 -> bn2/relu -> z@W3.T + b3, LDS-transposed coalesced store ----
__global__ __launch_bounds__(256, 4) void kF(const float* __restrict__ feats,
                                             const int* __restrict__ bidx,
                                             const float* __restrict__ wsf,
                                             const float* __restrict__ b3,
                                             float* __restrict__ out) {
  __shared__ __align__(16) unsigned char SB[36992];
  unsigned* zbuf = (unsigned*)SB;            // 32768 B: 4 waves x 64 rows x 128B
  float* Tl = (float*)(SB + 32768);          // 16*66
  float* fbuf = (float*)SB;                  // epilogue: [4][32][68] f32
  int tid = threadIdx.x;
  for (int i=tid;i<NB*64;i+=256) Tl[(i>>6)*66 + (i&63)] = wsf[WS_T + i];
  int lane = tid & 63, wv = tid >> 6;
  int col = lane & 15, kgrp = lane >> 4;
  const ushort* w3b = (const ushort*)((const unsigned*)wsf + WS_W3);
  bf16x8 bfr[4][2];
  #pragma unroll
  for (int n=0;n<4;n++)
    #pragma unroll
    for (int kk=0;kk<2;kk++)
      bfr[n][kk] = *(const bf16x8*)(w3b + (n*16+col)*64 + kk*32 + kgrp*8);
  float bias[4];
  #pragma unroll
  for (int n=0;n<4;n++) bias[n] = b3[n*16+col];
  __syncthreads();
  const float* Eg = wsf + WS_E;
  int p0 = (blockIdx.x*4 + wv)*64;
  int p = p0 + lane;
  float f0 = feats[3*p], f1 = feats[3*p+1], f2 = feats[3*p+2];
  int b = bidx[p];
  const float* tb = &Tl[b*66];
  unsigned rowbase = (unsigned)(wv*64+lane)*32;
  unsigned sw = (lane&7)<<2;
  #pragma unroll
  for (int j=0;j<8;j++){
    unsigned w[4];
    #pragma unroll
    for (int q=0;q<4;q++){
      int c = j*8 + q*2;
      float2 tp = *(const float2*)(tb + c);
      float y0 = fmaf(Eg[c],  f0, fmaf(Eg[64+c],  f1, fmaf(Eg[128+c],  f2, tp.x)));
      float y1 = fmaf(Eg[c+1],f0, fmaf(Eg[64+c+1],f1, fmaf(Eg[128+c+1],f2, tp.y)));
      w[q] = pack2bf(fmaxf(y0,0.f), fmaxf(y1,0.f));
    }
    uint4 ch; ch.x=w[0]; ch.y=w[1]; ch.z=w[2]; ch.w=w[3];
    *(uint4*)&zbuf[rowbase + (((unsigned)(j*4)) ^ sw)] = ch;
  }
  __syncthreads();
  bf16x8 af[4][2];
  #pragma unroll
  for (int m=0;m<4;m++){
    int row = m*16 + col;
    unsigned rb = (unsigned)(wv*64+row)*32;
    unsigned sw2 = (unsigned)(row&7)<<2;
    #pragma unroll
    for (int kk=0;kk<2;kk++){
      unsigned off = ((unsigned)(kk*16 + kgrp*4)) ^ sw2;
      af[m][kk] = *(const bf16x8*)&zbuf[rb + off];
    }
  }
  __syncthreads();
  #pragma unroll
  for (int half=0; half<2; half++){
    f32x4 acc[2][4];
    #pragma unroll
    for (int mi=0;mi<2;mi++)
      #pragma unroll
      for (int n=0;n<4;n++)
        acc[mi][n] = (f32x4){0.f,0.f,0.f,0.f};
    #pragma unroll
    for (int kk=0;kk<2;kk++)
      #pragma unroll
      for (int mi=0;mi<2;mi++)
        #pragma unroll
        for (int n=0;n<4;n++)
          acc[mi][n] = __builtin_amdgcn_mfma_f32_16x16x32_bf16(af[half*2+mi][kk], bfr[n][kk], acc[mi][n], 0,0,0);
    #pragma unroll
    for (int mi=0;mi<2;mi++){
      #pragma unroll
      for (int n=0;n<4;n++){
        #pragma unroll
        for (int r=0;r<4;r++)
          fbuf[wv*2176 + (mi*16 + kgrp*4 + r)*68 + n*16 + col] = acc[mi][n][r] + bias[n];
      }
    }
    __syncthreads();
    #pragma unroll
    for (int it=0; it<8; it++){
      int idx = it*256 + tid;
      int gr = idx >> 4;
      int c4 = (idx & 15) * 4;
      float4 v = *(const float4*)&fbuf[(gr>>5)*2176 + (gr&31)*68 + c4];
      int orow = blockIdx.x*256 + (gr>>5)*64 + half*32 + (gr&31);
      *(float4*)&out[(size_t)orow*64 + c4] = v;
    }
    __syncthreads();
  }
}

extern "C" void kernel_launch(void* const* d_in, const int* in_sizes, int n_in,
                              void* d_out, int out_size, void* d_ws, size_t ws_size,
                              hipStream_t stream) {
  const float* feats = (const float*)d_in[0];
  const int*   bidx  = (const int*)d_in[1];
  const float* W1 = (const float*)d_in[2];
  const float* g1 = (const float*)d_in[3];
  const float* b1 = (const float*)d_in[4];
  const float* W2 = (const float*)d_in[5];
  const float* g2 = (const float*)d_in[6];
  const float* b2 = (const float*)d_in[7];
  const float* W3 = (const float*)d_in[8];
  const float* b3 = (const float*)d_in[9];
  float* wsf = (float*)d_ws;
  float* out = (float*)d_out;
  kAC<<<ACBLK, 256, 0, stream>>>(feats, bidx, W1, g1, wsf);
  kMx<<<64, 256, 0, stream>>>(W3, wsf);
  kB2<<<64, 128, 0, stream>>>(W1, g1, b1, W2, g2, b2, wsf);
  kF<<<ACBLK, 256, 0, stream>>>(feats, bidx, wsf, b3, out);
}